// Round 16
// baseline (10188.699 us; speedup 1.0000x reference)
//
#include <hip/hip_runtime.h>
#include <stdint.h>

// BiRNN: 2-layer BiLSTM (U=256) + heads. B=32, T=2048, F=64.
// R16: single-WG-per-chain LSTM as a STANDALONE kernel with no MFMA anywhere
// in it (gfx950 gives MFMA kernels an accum_offset register split that capped
// arch VGPRs at 128 in R15's fused kernel and AGPR-parked the U array) and
// __launch_bounds__(512,1) (R13's (512,2) capped at 128 directly).
// Numerics identical to R15 (passed, absmax 3.9e-3): f16-pair U (32 pairs LDS
// + 96 pairs regs), h broadcast f16 hi+lo (exact), f16 xW chunks, f32 cell.
// GEMM back to standalone MFMA kernel (grid.z = dir), serial per chunk.

#define T_SEQ 2048
#define BATCH 32
#define NROWS 65536   // B*T
#define NG 1024       // 4*U

typedef __attribute__((ext_vector_type(8))) short short8;
typedef __attribute__((ext_vector_type(4))) float f32x4;
typedef __attribute__((ext_vector_type(2))) float f32x2;
typedef _Float16 f16x2 __attribute__((ext_vector_type(2)));

__device__ __forceinline__ ushort f32_to_bf16(float f) {
    uint32_t u = __float_as_uint(f);
    u = u + 0x7FFFu + ((u >> 16) & 1u);   // RNE
    return (ushort)(u >> 16);
}
__device__ __forceinline__ float bf16_to_f32(ushort h) {
    return __uint_as_float(((uint32_t)h) << 16);
}
__device__ __forceinline__ uint64_t split_pack4(f32x4 v, uint64_t& lo64) {
    ushort h0 = f32_to_bf16(v[0]), h1 = f32_to_bf16(v[1]);
    ushort h2 = f32_to_bf16(v[2]), h3 = f32_to_bf16(v[3]);
    ushort l0 = f32_to_bf16(v[0] - bf16_to_f32(h0));
    ushort l1 = f32_to_bf16(v[1] - bf16_to_f32(h1));
    ushort l2 = f32_to_bf16(v[2] - bf16_to_f32(h2));
    ushort l3 = f32_to_bf16(v[3] - bf16_to_f32(h3));
    lo64 = (uint64_t)l0 | ((uint64_t)l1 << 16) | ((uint64_t)l2 << 32) | ((uint64_t)l3 << 48);
    return (uint64_t)h0 | ((uint64_t)h1 << 16) | ((uint64_t)h2 << 32) | ((uint64_t)h3 << 48);
}
// acc += dot2(u, h) with f32 accumulate (V_DOT2_F32_F16)
__device__ __forceinline__ float fdot2_(uint32_t u, uint32_t h, float acc) {
    asm("v_dot2_f32_f16 %0, %1, %2, %0" : "+v"(acc) : "v"(u), "v"(h));
    return acc;
}

// U f32 [256][1024] -> Upk [kp][col] uint = half2(U[2kp][col], U[2kp+1][col])
__global__ void upack_kernel(const float* __restrict__ U, uint32_t* __restrict__ Upk) {
    int i = blockIdx.x * 256 + threadIdx.x;
    if (i >= 128 * 1024) return;
    int kp = i >> 10, col = i & 1023;
    f16x2 v;
    v[0] = (_Float16)U[(size_t)(2 * kp) * NG + col];
    v[1] = (_Float16)U[(size_t)(2 * kp + 1) * NG + col];
    Upk[i] = __builtin_bit_cast(uint32_t, v);
}

// ---- standalone GEMM (256 threads, MFMA): xW chunk, f16 out. dir = blockIdx.z
__global__ __launch_bounds__(256) void gemm_dual_kernel(
    const float* __restrict__ A, int K,
    const float* __restrict__ Wgf, const float* __restrict__ Wgb,
    const float* __restrict__ biasf, const float* __restrict__ biasb,
    ushort* __restrict__ xWnf, ushort* __restrict__ xWnb,
    int cb, int lsS)
{
    __shared__ __align__(16) ushort Ash[128 * 36];
    __shared__ __align__(16) ushort Asl[128 * 36];
    __shared__ __align__(16) ushort Bsh[128 * 36];
    __shared__ __align__(16) ushort Bsl[128 * 36];
    int dir = blockIdx.z;
    const float* Bw = dir ? Wgb : Wgf;
    const float* bias = dir ? biasb : biasf;
    ushort* Cc = dir ? xWnb : xWnf;
    int n0 = blockIdx.x * 128;
    int m0 = blockIdx.y * 128;

    const int Smask = (1 << lsS) - 1;
    int t = threadIdx.x;
    int lane = t & 63, wv = t >> 6;
    int wr = wv >> 1, wc = wv & 1;
    int fr = lane & 15, fq = lane >> 4;

    f32x4 acc[4][4];
#pragma unroll
    for (int i = 0; i < 4; i++)
#pragma unroll
        for (int j = 0; j < 4; j++) acc[i][j] = (f32x4)(0.0f);

    int arow = t >> 1, ahalf = t & 1;
    int bc = t & 127, bkh = t >> 7;

    int loc_all = m0 + arow;
    int b = loc_all >> lsS;
    int loc = loc_all & Smask;
    int row_g = b * T_SEQ + (dir ? (T_SEQ - 1 - cb - loc) : (cb + loc));

    for (int k0 = 0; k0 < K; k0 += 32) {
        {
            const float* s = A + (size_t)row_g * K + k0 + ahalf * 16;
            uint64_t* dh = (uint64_t*)&Ash[arow * 36 + ahalf * 16];
            uint64_t* dl = (uint64_t*)&Asl[arow * 36 + ahalf * 16];
#pragma unroll
            for (int g = 0; g < 4; g++) {
                f32x4 v = ((const f32x4*)s)[g];
                uint64_t lo64;
                uint64_t hi64 = split_pack4(v, lo64);
                dh[g] = hi64; dl[g] = lo64;
            }
        }
        {
            float bv[16];
#pragma unroll
            for (int i = 0; i < 16; i++)
                bv[i] = Bw[(size_t)(k0 + bkh * 16 + i) * NG + n0 + bc];
            uint64_t* dh = (uint64_t*)&Bsh[bc * 36 + bkh * 16];
            uint64_t* dl = (uint64_t*)&Bsl[bc * 36 + bkh * 16];
#pragma unroll
            for (int g = 0; g < 4; g++) {
                f32x4 v = { bv[4 * g], bv[4 * g + 1], bv[4 * g + 2], bv[4 * g + 3] };
                uint64_t lo64;
                uint64_t hi64 = split_pack4(v, lo64);
                dh[g] = hi64; dl[g] = lo64;
            }
        }
        __syncthreads();
        union FU { uint64_t u[2]; short8 v; };
        FU bh[4], bl[4];
#pragma unroll
        for (int n = 0; n < 4; n++) {
            int boff = (wc * 64 + n * 16 + fr) * 36 + fq * 8;
            bh[n].u[0] = ((const uint64_t*)&Bsh[boff])[0];
            bh[n].u[1] = ((const uint64_t*)&Bsh[boff])[1];
            bl[n].u[0] = ((const uint64_t*)&Bsl[boff])[0];
            bl[n].u[1] = ((const uint64_t*)&Bsl[boff])[1];
        }
#pragma unroll
        for (int m = 0; m < 4; m++) {
            int aoff = (wr * 64 + m * 16 + fr) * 36 + fq * 8;
            FU ah, al;
            ah.u[0] = ((const uint64_t*)&Ash[aoff])[0];
            ah.u[1] = ((const uint64_t*)&Ash[aoff])[1];
            al.u[0] = ((const uint64_t*)&Asl[aoff])[0];
            al.u[1] = ((const uint64_t*)&Asl[aoff])[1];
#pragma unroll
            for (int n = 0; n < 4; n++) {
                acc[m][n] = __builtin_amdgcn_mfma_f32_16x16x32_bf16(ah.v, bh[n].v, acc[m][n], 0, 0, 0);
                acc[m][n] = __builtin_amdgcn_mfma_f32_16x16x32_bf16(ah.v, bl[n].v, acc[m][n], 0, 0, 0);
                acc[m][n] = __builtin_amdgcn_mfma_f32_16x16x32_bf16(al.v, bh[n].v, acc[m][n], 0, 0, 0);
            }
        }
        __syncthreads();
    }
#pragma unroll
    for (int m = 0; m < 4; m++)
#pragma unroll
        for (int n = 0; n < 4; n++) {
            int gcol = n0 + wc * 64 + n * 16 + fr;
            float bvv = bias[gcol];
#pragma unroll
            for (int i = 0; i < 4; i++) {
                int crow = m0 + wr * 64 + m * 16 + fq * 4 + i;
                Cc[(size_t)crow * NG + gcol] =
                    __builtin_bit_cast(ushort, (_Float16)(acc[m][n][i] + bvv));
            }
        }
}

// ---- standalone LSTM: 64 WGs (one per chain), 512 threads, NO MFMA.
// Thread t owns cols 2t, 2t+1. U f16 pairs: 32 in LDS + 96x2 in VGPRs.
__global__ __launch_bounds__(512, 1) void lstm_kernel(
    const uint32_t* __restrict__ Upkf, const uint32_t* __restrict__ Upkb,
    const ushort* __restrict__ xWcf, const ushort* __restrict__ xWcb,  // f16 [B][S][NG]
    const int* __restrict__ mask,
    float* __restrict__ houtF, ushort* __restrict__ houtB,
    float* __restrict__ hstate, float* __restrict__ cstate,
    int cb, int S)
{
    int chain = blockIdx.x;
    int dir = chain >> 5;
    int b = chain & 31;
    const uint32_t* Upk = dir ? Upkb : Upkf;
    const ushort* xWc = dir ? xWcb : xWcf;

    int t = threadIdx.x;
    int c0 = 2 * t;

    __shared__ __align__(16) uint4 Ulds[16][512];   // 128 KB: pairs 0..31
    __shared__ __align__(16) uint32_t hsh[128];
    __shared__ __align__(16) uint32_t hsl[128];
    __shared__ __align__(16) float zsh[1024];
    __shared__ int mbuf[512];

#pragma unroll
    for (int r = 0; r < 16; r++) {
        uint4 v;
        v.x = Upk[(size_t)(2 * r) * NG + c0];
        v.y = Upk[(size_t)(2 * r) * NG + c0 + 1];
        v.z = Upk[(size_t)(2 * r + 1) * NG + c0];
        v.w = Upk[(size_t)(2 * r + 1) * NG + c0 + 1];
        Ulds[r][t] = v;
    }
    uint32_t Ua[96], Ub[96];
#pragma unroll
    for (int kp = 0; kp < 96; kp++) {
        Ua[kp] = Upk[(size_t)(32 + kp) * NG + c0];
        Ub[kp] = Upk[(size_t)(32 + kp) * NG + c0 + 1];
    }
    for (int nl = t; nl < S; nl += 512) {
        int tp = dir ? (T_SEQ - 1 - (cb + nl)) : (cb + nl);
        mbuf[nl] = mask[b * T_SEQ + tp];
    }
    float hreg = 0.0f, creg = 0.0f;
    if (t < 256) {
        if (cb != 0) {
            hreg = hstate[chain * 256 + t];
            creg = cstate[chain * 256 + t];
        }
        _Float16 hf = (_Float16)hreg;
        _Float16 hl16 = (_Float16)(hreg - (float)hf);
        ((ushort*)hsh)[t] = __builtin_bit_cast(ushort, hf);
        ((ushort*)hsl)[t] = __builtin_bit_cast(ushort, hl16);
    }
    __syncthreads();

    for (int nl = 0; nl < S; nl++) {
        int tp = dir ? (T_SEQ - 1 - (cb + nl)) : (cb + nl);
        size_t row_g = (size_t)b * T_SEQ + tp;
        if (mbuf[nl] == 1) {
            if (t < 256) {
                size_t oidx = row_g * 512 + dir * 256 + t;
                if (houtF) houtF[oidx] = hreg;
                else       houtB[oidx] = f32_to_bf16(hreg);
            }
            continue;
        }
        // active step
        uint32_t xu = *(const uint32_t*)(xWc + ((size_t)(b * S + nl)) * NG + c0);
        f16x2 xv = __builtin_bit_cast(f16x2, xu);
        float a0 = 0.0f, a1 = 0.0f;
        const uint4* hhp = (const uint4*)hsh;
        const uint4* hlp = (const uint4*)hsl;
        // LDS-U part: pairs 0..31 (h groups 0..7)
#pragma unroll
        for (int q = 0; q < 8; q++) {
            uint4 hh = hhp[q];
            uint4 hl = hlp[q];
            uint4 u0 = Ulds[2 * q][t];
            uint4 u1 = Ulds[2 * q + 1][t];
            a0 = fdot2_(u0.x, hh.x, a0); a1 = fdot2_(u0.y, hh.x, a1);
            a0 = fdot2_(u0.x, hl.x, a0); a1 = fdot2_(u0.y, hl.x, a1);
            a0 = fdot2_(u0.z, hh.y, a0); a1 = fdot2_(u0.w, hh.y, a1);
            a0 = fdot2_(u0.z, hl.y, a0); a1 = fdot2_(u0.w, hl.y, a1);
            a0 = fdot2_(u1.x, hh.z, a0); a1 = fdot2_(u1.y, hh.z, a1);
            a0 = fdot2_(u1.x, hl.z, a0); a1 = fdot2_(u1.y, hl.z, a1);
            a0 = fdot2_(u1.z, hh.w, a0); a1 = fdot2_(u1.w, hh.w, a1);
            a0 = fdot2_(u1.z, hl.w, a0); a1 = fdot2_(u1.w, hl.w, a1);
        }
        // reg part: pairs 32..127 (h groups 8..31)
#pragma unroll
        for (int i = 8; i < 32; i++) {
            uint4 hh = hhp[i];
            uint4 hl = hlp[i];
            int kp = 4 * i - 32;
            a0 = fdot2_(Ua[kp + 0], hh.x, a0); a1 = fdot2_(Ub[kp + 0], hh.x, a1);
            a0 = fdot2_(Ua[kp + 0], hl.x, a0); a1 = fdot2_(Ub[kp + 0], hl.x, a1);
            a0 = fdot2_(Ua[kp + 1], hh.y, a0); a1 = fdot2_(Ub[kp + 1], hh.y, a1);
            a0 = fdot2_(Ua[kp + 1], hl.y, a0); a1 = fdot2_(Ub[kp + 1], hl.y, a1);
            a0 = fdot2_(Ua[kp + 2], hh.z, a0); a1 = fdot2_(Ub[kp + 2], hh.z, a1);
            a0 = fdot2_(Ua[kp + 2], hl.z, a0); a1 = fdot2_(Ub[kp + 2], hl.z, a1);
            a0 = fdot2_(Ua[kp + 3], hh.w, a0); a1 = fdot2_(Ub[kp + 3], hh.w, a1);
            a0 = fdot2_(Ua[kp + 3], hl.w, a0); a1 = fdot2_(Ub[kp + 3], hl.w, a1);
        }
        zsh[c0]     = a0 + (float)xv[0];
        zsh[c0 + 1] = a1 + (float)xv[1];
        __syncthreads();   // partials ready
        if (t < 256) {
            float zi = zsh[t], zf = zsh[256 + t], zg = zsh[512 + t], zo = zsh[768 + t];
            float ig = 1.0f / (1.0f + expf(-zi));
            float fg = 1.0f / (1.0f + expf(-zf));
            float gg = tanhf(zg);
            float og = 1.0f / (1.0f + expf(-zo));
            float cn = fg * creg + ig * gg;
            float hn = og * tanhf(cn);
            creg = cn; hreg = hn;
            _Float16 hf = (_Float16)hn;
            _Float16 hl16 = (_Float16)(hn - (float)hf);
            ((ushort*)hsh)[t] = __builtin_bit_cast(ushort, hf);
            ((ushort*)hsl)[t] = __builtin_bit_cast(ushort, hl16);
            size_t oidx = row_g * 512 + dir * 256 + t;
            if (houtF) houtF[oidx] = hn;
            else       houtB[oidx] = f32_to_bf16(hn);
        }
        __syncthreads();   // new h visible; zsh reusable
    }
    if (t < 256) {
        hstate[chain * 256 + t] = hreg;
        cstate[chain * 256 + t] = creg;
    }
}

// heads: one wave per row; weights register-resident; shuffle reduce. h1 bf16.
__global__ __launch_bounds__(256, 2) void heads_kernel(
    const ushort* __restrict__ h1,
    const float* __restrict__ Wp, const float* __restrict__ bp,
    const float* __restrict__ Wbu, const float* __restrict__ bbu,
    const float* __restrict__ W3, const float* __restrict__ b3,
    const float* __restrict__ W8, const float* __restrict__ b8,
    const float* __restrict__ Wa, const float* __restrict__ ba,
    const float* __restrict__ Wpp, const float* __restrict__ bpp,
    float* __restrict__ out)
{
    int gwv = (blockIdx.x * 256 + threadIdx.x) >> 6;
    int nwv = (gridDim.x * 256) >> 6;
    int lane = threadIdx.x & 63;
    int k0 = lane * 8;

    float wr_[8][20];
#pragma unroll
    for (int u = 0; u < 8; u++) {
        int k = k0 + u;
        wr_[u][0]  = Wp[k * 2];      wr_[u][1]  = Wp[k * 2 + 1];
        wr_[u][2]  = Wbu[k * 2];     wr_[u][3]  = Wbu[k * 2 + 1];
        wr_[u][4]  = W3[k * 3];      wr_[u][5]  = W3[k * 3 + 1];  wr_[u][6] = W3[k * 3 + 2];
#pragma unroll
        for (int c = 0; c < 8; c++) wr_[u][7 + c] = W8[k * 8 + c];
        wr_[u][15] = Wa[k];
#pragma unroll
        for (int c = 0; c < 4; c++) wr_[u][16 + c] = Wpp[k * 4 + c];
    }
    float myb = 0.0f;
    size_t ooff = 0;
    if (lane < 2)        { myb = bp[lane];        ooff = 0 + lane; }
    else if (lane < 4)   { myb = bbu[lane - 2];   ooff = (size_t)NROWS * 2 + (lane - 2); }
    else if (lane < 7)   { myb = b3[lane - 4];    ooff = (size_t)NROWS * 4 + (lane - 4); }
    else if (lane < 15)  { myb = b8[lane - 7];    ooff = (size_t)NROWS * 7 + (lane - 7); }
    else if (lane < 16)  { myb = ba[0];           ooff = (size_t)NROWS * 15; }
    else if (lane < 20)  { myb = bpp[lane - 16];  ooff = (size_t)NROWS * 16 + (lane - 16); }
    float bp0 = bp[0], bp1 = bp[1];
    int stride = (lane < 2) ? 2 : (lane < 4) ? 2 : (lane < 7) ? 3 : (lane < 15) ? 8 : (lane < 16) ? 1 : 4;

    for (int r = gwv; r < NROWS; r += nwv) {
        union { uint4 u4; ushort us[8]; } hu;
        hu.u4 = *(const uint4*)(h1 + (size_t)r * 512 + k0);
        float acc[20];
#pragma unroll
        for (int c = 0; c < 20; c++) acc[c] = 0.0f;
#pragma unroll
        for (int u = 0; u < 8; u++) {
            float hv = fmaxf(bf16_to_f32(hu.us[u]), 0.0f);
#pragma unroll
            for (int c = 0; c < 20; c++) acc[c] += hv * wr_[u][c];
        }
#pragma unroll
        for (int off = 32; off >= 1; off >>= 1)
#pragma unroll
            for (int c = 0; c < 20; c++) acc[c] += __shfl_xor(acc[c], off);
        if (lane < 20) {
            float v = acc[lane] + myb;
            if (lane < 2) {
                float s0 = acc[0] + bp0, s1 = acc[1] + bp1;
                float mx = fmaxf(s0, s1);
                float e0 = expf(s0 - mx), e1 = expf(s1 - mx);
                v = ((lane == 0) ? e0 : e1) / (e0 + e1);
            }
            out[ooff + (size_t)r * stride] = v;
        }
    }
}

extern "C" void kernel_launch(void* const* d_in, const int* in_sizes, int n_in,
                              void* d_out, int out_size, void* d_ws, size_t ws_size,
                              hipStream_t stream) {
    const float* x    = (const float*)d_in[0];
    const int* xmask  = (const int*)d_in[1];
    const float* Wf0  = (const float*)d_in[3];
    const float* Uf0  = (const float*)d_in[4];
    const float* bf0  = (const float*)d_in[5];
    const float* Wb0  = (const float*)d_in[6];
    const float* Ub0  = (const float*)d_in[7];
    const float* bb0  = (const float*)d_in[8];
    const float* Wf1  = (const float*)d_in[9];
    const float* Uf1  = (const float*)d_in[10];
    const float* bf1  = (const float*)d_in[11];
    const float* Wb1  = (const float*)d_in[12];
    const float* Ub1  = (const float*)d_in[13];
    const float* bb1  = (const float*)d_in[14];
    const float* Wp   = (const float*)d_in[15]; const float* bp  = (const float*)d_in[16];
    const float* Wbu  = (const float*)d_in[17]; const float* bbu = (const float*)d_in[18];
    const float* W3   = (const float*)d_in[19]; const float* b3  = (const float*)d_in[20];
    const float* W8   = (const float*)d_in[21]; const float* b8  = (const float*)d_in[22];
    const float* Wa   = (const float*)d_in[23]; const float* ba  = (const float*)d_in[24];
    const float* Wpp  = (const float*)d_in[25]; const float* bpp = (const float*)d_in[26];
    float* out = (float*)d_out;

    char* ws = (char*)d_ws;
    size_t off = 0;
    auto take = [&](size_t bytes) -> void* {
        void* p = ws + off;
        off += (bytes + 255) & ~(size_t)255;
        return p;
    };
    uint32_t* U0f = (uint32_t*)take((size_t)128 * 1024 * 4);
    uint32_t* U0b = (uint32_t*)take((size_t)128 * 1024 * 4);
    uint32_t* U1f = (uint32_t*)take((size_t)128 * 1024 * 4);
    uint32_t* U1b = (uint32_t*)take((size_t)128 * 1024 * 4);
    float*  hstate = (float*)take((size_t)64 * 256 * 4);
    float*  cstate = (float*)take((size_t)64 * 256 * 4);
    float*  h0F    = (float*)take((size_t)NROWS * 512 * 4);    // 134.2 MB (f32)
    ushort* h1B    = (ushort*)take((size_t)NROWS * 512 * 2);   // 67.1 MB (bf16)
    size_t fixed = off;

    // 2 xW f16 buffers (one per dir), each S*65536 bytes
    int S = 8, lsS = 3;
    for (int cand = 9; cand >= 3; cand--) {
        if (fixed + 2 * (((size_t)1 << cand) * 65536) + 4096 <= ws_size) { S = 1 << cand; lsS = cand; break; }
    }
    ushort* xWf = (ushort*)take((size_t)BATCH * S * NG * 2);
    ushort* xWb = (ushort*)take((size_t)BATCH * S * NG * 2);
    int NC = T_SEQ / S;
    dim3 ggrid(8, (BATCH * S) / 128, 2);
    (void)in_sizes; (void)n_in; (void)out_size;

    upack_kernel<<<512, 256, 0, stream>>>(Uf0, U0f);
    upack_kernel<<<512, 256, 0, stream>>>(Ub0, U0b);
    upack_kernel<<<512, 256, 0, stream>>>(Uf1, U1f);
    upack_kernel<<<512, 256, 0, stream>>>(Ub1, U1b);

    // layer 0: A = x (K=64), lstm writes h0F (f32)
    for (int c = 0; c < NC; c++) {
        int cb = c * S;
        gemm_dual_kernel<<<ggrid, 256, 0, stream>>>(x, 64, Wf0, Wb0, bf0, bb0, xWf, xWb, cb, lsS);
        lstm_kernel<<<64, 512, 0, stream>>>(U0f, U0b, xWf, xWb, xmask, h0F, nullptr,
                                            hstate, cstate, cb, S);
    }
    // layer 1: A = h0F (K=512, read-only), lstm writes h1B (bf16)
    for (int c = 0; c < NC; c++) {
        int cb = c * S;
        gemm_dual_kernel<<<ggrid, 256, 0, stream>>>(h0F, 512, Wf1, Wb1, bf1, bb1, xWf, xWb, cb, lsS);
        lstm_kernel<<<64, 512, 0, stream>>>(U1f, U1b, xWf, xWb, xmask, nullptr, h1B,
                                            hstate, cstate, cb, S);
    }

    heads_kernel<<<2048, 256, 0, stream>>>(
        h1B, Wp, bp, Wbu, bbu, W3, b3, W8, b8, Wa, ba, Wpp, bpp, out);
}

// Round 17
// 5449.244 us; speedup vs baseline: 1.8697x; 1.8697x over previous
//
#include <hip/hip_runtime.h>
#include <stdint.h>

// BiRNN: 2-layer BiLSTM (U=256) + heads. B=32, T=2048, F=64.
// R17 = R11 (4-WG/chain, packed {h,cnt} LLC exchange, mask-skip; the proven
// 5.6ms structure) + GEMM fusion at S=128: xW chunks stored f16 so FOUR
// double-buffered chunk buffers fit in ws (R14's f32 version forced S=64 and
// was neutral). Blocks 0..255 run lstm(chunk c); blocks 256+ run gemm(c+1).
// gemm blocks retire unconditionally -> no deadlock. f16-xW noise ~2.4e-4,
// below the stable 3.9e-3 absmax floor (validated in R15/R16).

#define T_SEQ 2048
#define BATCH 32
#define NROWS 65536   // B*T
#define NG 1024       // 4*U
#define FLG_STRIDE 32 // ints per chain (128 B)

typedef __attribute__((ext_vector_type(8))) short short8;
typedef __attribute__((ext_vector_type(4))) float f32x4;
typedef __attribute__((ext_vector_type(2))) float f32x2;
typedef _Float16 f16x2 __attribute__((ext_vector_type(2)));

__device__ __forceinline__ ushort f32_to_bf16(float f) {
    uint32_t u = __float_as_uint(f);
    u = u + 0x7FFFu + ((u >> 16) & 1u);   // RNE
    return (ushort)(u >> 16);
}
__device__ __forceinline__ float bf16_to_f32(ushort h) {
    return __uint_as_float(((uint32_t)h) << 16);
}
__device__ __forceinline__ float f16u_to_f32(ushort h) {
    return (float)__builtin_bit_cast(_Float16, h);
}
__device__ __forceinline__ ushort f32_to_f16u(float f) {
    return __builtin_bit_cast(ushort, (_Float16)f);
}
__device__ __forceinline__ uint64_t split_pack4(f32x4 v, uint64_t& lo64) {
    ushort h0 = f32_to_bf16(v[0]), h1 = f32_to_bf16(v[1]);
    ushort h2 = f32_to_bf16(v[2]), h3 = f32_to_bf16(v[3]);
    ushort l0 = f32_to_bf16(v[0] - bf16_to_f32(h0));
    ushort l1 = f32_to_bf16(v[1] - bf16_to_f32(h1));
    ushort l2 = f32_to_bf16(v[2] - bf16_to_f32(h2));
    ushort l3 = f32_to_bf16(v[3] - bf16_to_f32(h3));
    lo64 = (uint64_t)l0 | ((uint64_t)l1 << 16) | ((uint64_t)l2 << 32) | ((uint64_t)l3 << 48);
    return (uint64_t)h0 | ((uint64_t)h1 << 16) | ((uint64_t)h2 << 32) | ((uint64_t)h3 << 48);
}

__global__ void init_ctrl_kernel(int* __restrict__ flags, int nf,
                                 unsigned long long* __restrict__ hxp, int nh) {
    int i = blockIdx.x * 256 + threadIdx.x;
    if (i < nf) flags[i] = 0;
    if (i < nh) hxp[i] = 0ull;
}

struct __align__(16) GemmSh {
    ushort Ash[128 * 36];
    ushort Asl[128 * 36];
    ushort Bsh[128 * 36];
    ushort Bsl[128 * 36];
};
struct __align__(16) LstmSh {
    float hbuf[256];
    float pbuf[1024];
    int mbuf[2048];
};
union __align__(16) ShU { GemmSh g; LstmSh l; };

// ---- GEMM body (256 threads): Cc = A@Bw + bias, f16 out (3-term bf16 split)
__device__ void gemm_body(GemmSh& sh,
    const float* __restrict__ A, int K,
    const float* __restrict__ Bw, const float* __restrict__ bias,
    ushort* __restrict__ Cc, int cb, int lsS, int dir, int n0, int m0)
{
    const int Smask = (1 << lsS) - 1;
    int t = threadIdx.x;
    int lane = t & 63, wv = t >> 6;
    int wr = wv >> 1, wc = wv & 1;
    int fr = lane & 15, fq = lane >> 4;

    f32x4 acc[4][4];
#pragma unroll
    for (int i = 0; i < 4; i++)
#pragma unroll
        for (int j = 0; j < 4; j++) acc[i][j] = (f32x4)(0.0f);

    int arow = t >> 1, ahalf = t & 1;
    int bc = t & 127, bkh = t >> 7;

    int loc_all = m0 + arow;
    int b = loc_all >> lsS;
    int loc = loc_all & Smask;
    int row_g = b * T_SEQ + (dir ? (T_SEQ - 1 - cb - loc) : (cb + loc));

    for (int k0 = 0; k0 < K; k0 += 32) {
        {
            const float* s = A + (size_t)row_g * K + k0 + ahalf * 16;
            uint64_t* dh = (uint64_t*)&sh.Ash[arow * 36 + ahalf * 16];
            uint64_t* dl = (uint64_t*)&sh.Asl[arow * 36 + ahalf * 16];
#pragma unroll
            for (int g = 0; g < 4; g++) {
                f32x4 v = ((const f32x4*)s)[g];
                uint64_t lo64;
                uint64_t hi64 = split_pack4(v, lo64);
                dh[g] = hi64; dl[g] = lo64;
            }
        }
        {
            float bv[16];
#pragma unroll
            for (int i = 0; i < 16; i++)
                bv[i] = Bw[(size_t)(k0 + bkh * 16 + i) * NG + n0 + bc];
            uint64_t* dh = (uint64_t*)&sh.Bsh[bc * 36 + bkh * 16];
            uint64_t* dl = (uint64_t*)&sh.Bsl[bc * 36 + bkh * 16];
#pragma unroll
            for (int g = 0; g < 4; g++) {
                f32x4 v = { bv[4 * g], bv[4 * g + 1], bv[4 * g + 2], bv[4 * g + 3] };
                uint64_t lo64;
                uint64_t hi64 = split_pack4(v, lo64);
                dh[g] = hi64; dl[g] = lo64;
            }
        }
        __syncthreads();
        union FU { uint64_t u[2]; short8 v; };
        FU bh[4], bl[4];
#pragma unroll
        for (int n = 0; n < 4; n++) {
            int boff = (wc * 64 + n * 16 + fr) * 36 + fq * 8;
            bh[n].u[0] = ((const uint64_t*)&sh.Bsh[boff])[0];
            bh[n].u[1] = ((const uint64_t*)&sh.Bsh[boff])[1];
            bl[n].u[0] = ((const uint64_t*)&sh.Bsl[boff])[0];
            bl[n].u[1] = ((const uint64_t*)&sh.Bsl[boff])[1];
        }
#pragma unroll
        for (int m = 0; m < 4; m++) {
            int aoff = (wr * 64 + m * 16 + fr) * 36 + fq * 8;
            FU ah, al;
            ah.u[0] = ((const uint64_t*)&sh.Ash[aoff])[0];
            ah.u[1] = ((const uint64_t*)&sh.Ash[aoff])[1];
            al.u[0] = ((const uint64_t*)&sh.Asl[aoff])[0];
            al.u[1] = ((const uint64_t*)&sh.Asl[aoff])[1];
#pragma unroll
            for (int n = 0; n < 4; n++) {
                acc[m][n] = __builtin_amdgcn_mfma_f32_16x16x32_bf16(ah.v, bh[n].v, acc[m][n], 0, 0, 0);
                acc[m][n] = __builtin_amdgcn_mfma_f32_16x16x32_bf16(ah.v, bl[n].v, acc[m][n], 0, 0, 0);
                acc[m][n] = __builtin_amdgcn_mfma_f32_16x16x32_bf16(al.v, bh[n].v, acc[m][n], 0, 0, 0);
            }
        }
        __syncthreads();
    }
#pragma unroll
    for (int m = 0; m < 4; m++)
#pragma unroll
        for (int n = 0; n < 4; n++) {
            int gcol = n0 + wc * 64 + n * 16 + fr;
            float bvv = bias[gcol];
#pragma unroll
            for (int i = 0; i < 4; i++) {
                int crow = m0 + wr * 64 + m * 16 + fq * 4 + i;
                Cc[(size_t)crow * NG + gcol] = f32_to_f16u(acc[m][n][i] + bvv);
            }
        }
}

// ---- fused: blocks 0..255 lstm(chunk cb) [R11 body]; blocks 256+ gemm(cbn)
__global__ __launch_bounds__(512, 2) void fused_kernel(
    // lstm
    const float* __restrict__ Uf, const float* __restrict__ Ub,
    const ushort* __restrict__ xWcf, const ushort* __restrict__ xWcb, // f16 [B][S][NG]
    const int* __restrict__ mask,
    float* __restrict__ houtF, ushort* __restrict__ houtB,
    unsigned long long* __restrict__ hxp, float* __restrict__ cstate,
    int* __restrict__ flags, int cb, int S, int has_lstm,
    // gemm (next chunk)
    const float* __restrict__ A, int K,
    const float* __restrict__ Wgf, const float* __restrict__ Wgb,
    const float* __restrict__ biasf, const float* __restrict__ biasb,
    ushort* __restrict__ xWnf, ushort* __restrict__ xWnb,
    int cbn, int lsS, int mtiles)
{
    __shared__ ShU sh;
    if (blockIdx.x >= 256) {
        // ---- GEMM branch ----
        if (cbn >= T_SEQ) return;
        if (threadIdx.x >= 256) return;
        int gb = blockIdx.x - 256;
        int half = 8 * mtiles;
        int dirg = gb >= half ? 1 : 0;
        int gbb = dirg ? gb - half : gb;
        int n0 = (gbb & 7) * 128;
        int m0 = (gbb >> 3) * 128;
        gemm_body(sh.g, A, K, dirg ? Wgb : Wgf, dirg ? biasb : biasf,
                  dirg ? xWnb : xWnf, cbn, lsS, dirg, n0, m0);
        return;
    }
    // ---- LSTM branch (R11 body, f16 xW reads) ----
    if (!has_lstm) return;
    int wg = blockIdx.x;
    int chain = wg & 63;
    int w = wg >> 6;
    int dir = chain >> 5;
    int b = chain & 31;
    const float* U = dir ? Ub : Uf;
    const ushort* xWc = dir ? xWcb : xWcf;

    int t = threadIdx.x;
    float* hbuf = sh.l.hbuf;
    float* pbuf = sh.l.pbuf;
    int* mbuf = sh.l.mbuf;

    int kchunk = t >> 7;
    int cg = t & 127;
    int q = cg >> 5;
    int jj0 = 2 * (cg & 31);
    int col0 = q * 256 + w * 64 + jj0;

    f32x2 Ur[64];
    {
        const float* Up = U + (size_t)(kchunk * 64) * NG + col0;
#pragma unroll
        for (int i = 0; i < 64; i++) Ur[i] = *(const f32x2*)(Up + (size_t)i * NG);
    }
    unsigned long long* hxpc = hxp + chain * 512;
    int* flg = flags + chain * FLG_STRIDE;
    int j = t & 63;
    int gj = w * 64 + j;
    int owner = t >> 6;

    for (int nl = t; nl < S; nl += 512) {
        int tp = dir ? (T_SEQ - 1 - (cb + nl)) : (cb + nl);
        mbuf[nl] = mask[b * T_SEQ + tp];
    }
    int kc = __hip_atomic_load(&flg[0], __ATOMIC_RELAXED, __HIP_MEMORY_SCOPE_AGENT);
    if (t < 256) {
        if (kc > 0) {
            unsigned long long pk = __hip_atomic_load(&hxpc[((kc - 1) & 1) * 256 + t],
                                                      __ATOMIC_RELAXED, __HIP_MEMORY_SCOPE_AGENT);
            hbuf[t] = __uint_as_float((uint32_t)pk);
        } else {
            hbuf[t] = 0.0f;
        }
    }
    float creg = 0.0f, hreg = 0.0f;
    if (t < 64) {
        if (cb != 0) creg = cstate[chain * 256 + gj];
        if (kc > 0) {
            unsigned long long pk = __hip_atomic_load(&hxpc[((kc - 1) & 1) * 256 + gj],
                                                      __ATOMIC_RELAXED, __HIP_MEMORY_SCOPE_AGENT);
            hreg = __uint_as_float((uint32_t)pk);
        }
    }
    __syncthreads();

    for (int nl = 0; nl < S; nl++) {
        int tp = dir ? (T_SEQ - 1 - (cb + nl)) : (cb + nl);
        size_t row_g = (size_t)b * T_SEQ + tp;
        int mval = mbuf[nl];
        if (mval == 1) {
            if (t < 64) {
                size_t oidx = row_g * 512 + dir * 256 + gj;
                if (houtF) houtF[oidx] = hreg;
                else       houtB[oidx] = f32_to_bf16(hreg);
            }
            continue;
        }
        float xw0 = 0.f, xw1 = 0.f, xw2 = 0.f, xw3 = 0.f;
        if (t < 64) {
            const ushort* xr = xWc + ((size_t)b * S + nl) * NG;
            xw0 = f16u_to_f32(xr[gj]);
            xw1 = f16u_to_f32(xr[256 + gj]);
            xw2 = f16u_to_f32(xr[512 + gj]);
            xw3 = f16u_to_f32(xr[768 + gj]);
        }
        if (kc > 0 && t < 256 && owner != w) {
            unsigned long long pk;
            for (;;) {
                pk = __hip_atomic_load(&hxpc[((kc - 1) & 1) * 256 + t],
                                       __ATOMIC_RELAXED, __HIP_MEMORY_SCOPE_AGENT);
                if ((uint32_t)(pk >> 32) >= (uint32_t)kc) break;
                __builtin_amdgcn_s_sleep(1);
            }
            hbuf[t] = __uint_as_float((uint32_t)pk);
        }
        __syncthreads();   // (C)
        float a0 = 0.0f, a1 = 0.0f;
        {
            const float* hb = &hbuf[kchunk * 64];
#pragma unroll
            for (int i = 0; i < 16; i++) {
                f32x4 h4 = *(const f32x4*)(hb + 4 * i);
#pragma unroll
                for (int j2 = 0; j2 < 4; j2++) {
                    a0 += h4[j2] * Ur[4 * i + j2][0];
                    a1 += h4[j2] * Ur[4 * i + j2][1];
                }
            }
        }
        {
            f32x2 pv = {a0, a1};
            *(f32x2*)&pbuf[kchunk * 256 + 2 * cg] = pv;
        }
        __syncthreads();   // (E)
        if (t < 64) {
            float zi = xw0 + pbuf[j]       + pbuf[256 + j]       + pbuf[512 + j]       + pbuf[768 + j];
            float zf = xw1 + pbuf[64 + j]  + pbuf[256 + 64 + j]  + pbuf[512 + 64 + j]  + pbuf[768 + 64 + j];
            float zg = xw2 + pbuf[128 + j] + pbuf[256 + 128 + j] + pbuf[512 + 128 + j] + pbuf[768 + 128 + j];
            float zo = xw3 + pbuf[192 + j] + pbuf[256 + 192 + j] + pbuf[512 + 192 + j] + pbuf[768 + 192 + j];
            float ig = 1.0f / (1.0f + expf(-zi));
            float fg = 1.0f / (1.0f + expf(-zf));
            float gg = tanhf(zg);
            float og = 1.0f / (1.0f + expf(-zo));
            float cn = fg * creg + ig * gg;
            float hn = og * tanhf(cn);
            creg = cn; hreg = hn;
            hbuf[gj] = hn;
            unsigned long long pk = ((unsigned long long)(uint32_t)(kc + 1) << 32)
                                  | (unsigned long long)(uint32_t)__float_as_uint(hn);
            __hip_atomic_store(&hxpc[(kc & 1) * 256 + gj], pk,
                               __ATOMIC_RELAXED, __HIP_MEMORY_SCOPE_AGENT);
            size_t oidx = row_g * 512 + dir * 256 + gj;
            if (houtF) houtF[oidx] = hn;
            else       houtB[oidx] = f32_to_bf16(hn);
        }
        kc++;
    }
    if (t < 64) cstate[chain * 256 + gj] = creg;
    if (w == 0 && t == 0)
        __hip_atomic_store(&flg[0], kc, __ATOMIC_RELAXED, __HIP_MEMORY_SCOPE_AGENT);
}

// heads: one wave per row; 20 head-weights register-resident; shuffle reduce.
__global__ __launch_bounds__(256, 2) void heads_kernel(
    const ushort* __restrict__ h1,   // [NROWS][512] bf16
    const float* __restrict__ Wp, const float* __restrict__ bp,
    const float* __restrict__ Wbu, const float* __restrict__ bbu,
    const float* __restrict__ W3, const float* __restrict__ b3,
    const float* __restrict__ W8, const float* __restrict__ b8,
    const float* __restrict__ Wa, const float* __restrict__ ba,
    const float* __restrict__ Wpp, const float* __restrict__ bpp,
    float* __restrict__ out)
{
    int gwv = (blockIdx.x * 256 + threadIdx.x) >> 6;
    int nwv = (gridDim.x * 256) >> 6;
    int lane = threadIdx.x & 63;
    int k0 = lane * 8;

    float wr_[8][20];
#pragma unroll
    for (int u = 0; u < 8; u++) {
        int k = k0 + u;
        wr_[u][0]  = Wp[k * 2];      wr_[u][1]  = Wp[k * 2 + 1];
        wr_[u][2]  = Wbu[k * 2];     wr_[u][3]  = Wbu[k * 2 + 1];
        wr_[u][4]  = W3[k * 3];      wr_[u][5]  = W3[k * 3 + 1];  wr_[u][6] = W3[k * 3 + 2];
#pragma unroll
        for (int c = 0; c < 8; c++) wr_[u][7 + c] = W8[k * 8 + c];
        wr_[u][15] = Wa[k];
#pragma unroll
        for (int c = 0; c < 4; c++) wr_[u][16 + c] = Wpp[k * 4 + c];
    }
    float myb = 0.0f;
    size_t ooff = 0;
    if (lane < 2)        { myb = bp[lane];        ooff = 0 + lane; }
    else if (lane < 4)   { myb = bbu[lane - 2];   ooff = (size_t)NROWS * 2 + (lane - 2); }
    else if (lane < 7)   { myb = b3[lane - 4];    ooff = (size_t)NROWS * 4 + (lane - 4); }
    else if (lane < 15)  { myb = b8[lane - 7];    ooff = (size_t)NROWS * 7 + (lane - 7); }
    else if (lane < 16)  { myb = ba[0];           ooff = (size_t)NROWS * 15; }
    else if (lane < 20)  { myb = bpp[lane - 16];  ooff = (size_t)NROWS * 16 + (lane - 16); }
    float bp0 = bp[0], bp1 = bp[1];
    int stride = (lane < 2) ? 2 : (lane < 4) ? 2 : (lane < 7) ? 3 : (lane < 15) ? 8 : (lane < 16) ? 1 : 4;

    for (int r = gwv; r < NROWS; r += nwv) {
        union { uint4 u4; ushort us[8]; } hu;
        hu.u4 = *(const uint4*)(h1 + (size_t)r * 512 + k0);
        float acc[20];
#pragma unroll
        for (int c = 0; c < 20; c++) acc[c] = 0.0f;
#pragma unroll
        for (int u = 0; u < 8; u++) {
            float hv = fmaxf(bf16_to_f32(hu.us[u]), 0.0f);
#pragma unroll
            for (int c = 0; c < 20; c++) acc[c] += hv * wr_[u][c];
        }
#pragma unroll
        for (int off = 32; off >= 1; off >>= 1)
#pragma unroll
            for (int c = 0; c < 20; c++) acc[c] += __shfl_xor(acc[c], off);
        if (lane < 20) {
            float v = acc[lane] + myb;
            if (lane < 2) {
                float s0 = acc[0] + bp0, s1 = acc[1] + bp1;
                float mx = fmaxf(s0, s1);
                float e0 = expf(s0 - mx), e1 = expf(s1 - mx);
                v = ((lane == 0) ? e0 : e1) / (e0 + e1);
            }
            out[ooff + (size_t)r * stride] = v;
        }
    }
}

extern "C" void kernel_launch(void* const* d_in, const int* in_sizes, int n_in,
                              void* d_out, int out_size, void* d_ws, size_t ws_size,
                              hipStream_t stream) {
    const float* x    = (const float*)d_in[0];
    const int* xmask  = (const int*)d_in[1];
    const float* Wf0  = (const float*)d_in[3];
    const float* Uf0  = (const float*)d_in[4];
    const float* bf0  = (const float*)d_in[5];
    const float* Wb0  = (const float*)d_in[6];
    const float* Ub0  = (const float*)d_in[7];
    const float* bb0  = (const float*)d_in[8];
    const float* Wf1  = (const float*)d_in[9];
    const float* Uf1  = (const float*)d_in[10];
    const float* bf1  = (const float*)d_in[11];
    const float* Wb1  = (const float*)d_in[12];
    const float* Ub1  = (const float*)d_in[13];
    const float* bb1  = (const float*)d_in[14];
    const float* Wp   = (const float*)d_in[15]; const float* bp  = (const float*)d_in[16];
    const float* Wbu  = (const float*)d_in[17]; const float* bbu = (const float*)d_in[18];
    const float* W3   = (const float*)d_in[19]; const float* b3  = (const float*)d_in[20];
    const float* W8   = (const float*)d_in[21]; const float* b8  = (const float*)d_in[22];
    const float* Wa   = (const float*)d_in[23]; const float* ba  = (const float*)d_in[24];
    const float* Wpp  = (const float*)d_in[25]; const float* bpp = (const float*)d_in[26];
    float* out = (float*)d_out;

    char* ws = (char*)d_ws;
    size_t off = 0;
    auto take = [&](size_t bytes) -> void* {
        void* p = ws + off;
        off += (bytes + 255) & ~(size_t)255;
        return p;
    };
    int* flags = (int*)take((size_t)2 * 64 * FLG_STRIDE * 4);
    unsigned long long* hxp = (unsigned long long*)take((size_t)2 * 64 * 2 * 256 * 8);
    float*  cstate = (float*)take((size_t)64 * 256 * 4);
    float*  h0F    = (float*)take((size_t)NROWS * 512 * 4);    // 134.2 MB (f32)
    ushort* h1B    = (ushort*)take((size_t)NROWS * 512 * 2);   // 67.1 MB (bf16)
    size_t fixed = off;

    // 4 xW f16 buffers (2 dirs x 2 parity), each S*65536 bytes
    int S = 8, lsS = 3;
    for (int cand = 9; cand >= 3; cand--) {
        if (fixed + 4 * (((size_t)1 << cand) * 65536) + 4096 <= ws_size) { S = 1 << cand; lsS = cand; break; }
    }
    ushort* xWf[2]; ushort* xWb[2];
    xWf[0] = (ushort*)take((size_t)BATCH * S * NG * 2);
    xWb[0] = (ushort*)take((size_t)BATCH * S * NG * 2);
    xWf[1] = (ushort*)take((size_t)BATCH * S * NG * 2);
    xWb[1] = (ushort*)take((size_t)BATCH * S * NG * 2);
    int NC = T_SEQ / S;
    int mtiles = (BATCH * S) / 128;
    int NGB = 2 * 8 * mtiles;
    dim3 fgrid(256 + NGB);
    (void)in_sizes; (void)n_in; (void)out_size;

    int nf = 2 * 64 * FLG_STRIDE;
    int nh = 2 * 64 * 2 * 256;
    int ninit = nh > nf ? nh : nf;
    init_ctrl_kernel<<<(ninit + 255) / 256, 256, 0, stream>>>(flags, nf, hxp, nh);

    // ---- layer 0: gemm A = x (K=64); lstm writes h0F (f32) ----
    fused_kernel<<<fgrid, 512, 0, stream>>>(
        Uf0, Ub0, xWf[0], xWb[0], xmask, h0F, nullptr, hxp, cstate, flags, 0, S, 0,
        x, 64, Wf0, Wb0, bf0, bb0, xWf[0], xWb[0], 0, lsS, mtiles);
    for (int c = 0; c < NC; c++) {
        int cb = c * S;
        int cbn = (c + 1) * S;
        fused_kernel<<<fgrid, 512, 0, stream>>>(
            Uf0, Ub0, xWf[c & 1], xWb[c & 1], xmask, h0F, nullptr, hxp, cstate, flags, cb, S, 1,
            x, 64, Wf0, Wb0, bf0, bb0, xWf[(c + 1) & 1], xWb[(c + 1) & 1], cbn, lsS, mtiles);
    }
    // ---- layer 1: gemm A = h0F (K=512, fully written); lstm writes h1B ----
    fused_kernel<<<fgrid, 512, 0, stream>>>(
        Uf1, Ub1, xWf[0], xWb[0], xmask, nullptr, h1B, hxp + (size_t)64 * 512, cstate,
        flags + 64 * FLG_STRIDE, 0, S, 0,
        h0F, 512, Wf1, Wb1, bf1, bb1, xWf[0], xWb[0], 0, lsS, mtiles);
    for (int c = 0; c < NC; c++) {
        int cb = c * S;
        int cbn = (c + 1) * S;
        fused_kernel<<<fgrid, 512, 0, stream>>>(
            Uf1, Ub1, xWf[c & 1], xWb[c & 1], xmask, nullptr, h1B, hxp + (size_t)64 * 512, cstate,
            flags + 64 * FLG_STRIDE, cb, S, 1,
            h0F, 512, Wf1, Wb1, bf1, bb1, xWf[(c + 1) & 1], xWb[(c + 1) & 1], cbn, lsS, mtiles);
    }

    heads_kernel<<<2048, 256, 0, stream>>>(
        h1B, Wp, bp, Wbu, bbu, W3, b3, W8, b8, Wa, ba, Wpp, bpp, out);
}